// Round 7
// baseline (205.544 us; speedup 1.0000x reference)
//
#include <hip/hip_runtime.h>

#define N_NODES 100000
#define N_FEATS 256
#define OUT_DIM 64
#define NNZ_X   1280000
#define N_EDGES 1600000
#define NBH     782     // ceil(N_NODES/128); bucket = row >> 7 (half-buckets)
#define CHUNK   4096    // entries per phase-1 block (512 thr, 8/thread)
#define KPT     8
#define CAPXH   2560    // X half-slab capacity (kept-mean 1473, sigma ~38: +28 sigma)
#define CAPAH   3072    // A half-slab capacity (mean 2046, sigma ~45: +22 sigma)
#define XW_ROWS 100096  // padded row count; xw layout = [4 slices][XW_ROWS][16 dims bf16]

// ---------------- JAX threefry2x32 (partitionable mode, verified R2) ----------------
__device__ __forceinline__ unsigned rotl32(unsigned x, unsigned d) {
    return (x << d) | (x >> (32u - d));
}

__device__ __forceinline__ float jax_uniform_42(unsigned e) {
    unsigned x0 = 0u, x1 = e;
    const unsigned ks0 = 0u, ks1 = 42u, ks2 = 0u ^ 42u ^ 0x1BD11BDAu;
    x0 += ks0; x1 += ks1;
#define TF_R(r) { x0 += x1; x1 = rotl32(x1, r); x1 ^= x0; }
    TF_R(13) TF_R(15) TF_R(26) TF_R(6)
    x0 += ks1; x1 += ks2 + 1u;
    TF_R(17) TF_R(29) TF_R(16) TF_R(24)
    x0 += ks2; x1 += ks0 + 2u;
    TF_R(13) TF_R(15) TF_R(26) TF_R(6)
    x0 += ks0; x1 += ks1 + 3u;
    TF_R(17) TF_R(29) TF_R(16) TF_R(24)
    x0 += ks1; x1 += ks2 + 4u;
    TF_R(13) TF_R(15) TF_R(26) TF_R(6)
    x0 += ks2; x1 += ks0 + 5u;
#undef TF_R
    unsigned bits = x0 ^ x1;
    return __uint_as_float((bits >> 9) | 0x3f800000u) - 1.0f;
}

__device__ __forceinline__ bool keep_42(unsigned e) {
    float u = jax_uniform_42(e);
    return floorf(0.9f + u) != 0.0f;
}

// f32 -> bf16 round-to-nearest-even
__device__ __forceinline__ unsigned short f32_bf16(float f) {
    unsigned bits = __float_as_uint(f);
    return (unsigned short)((bits + 0x7fffu + ((bits >> 16) & 1u)) >> 16);
}

__device__ __forceinline__ float bflo(unsigned u) { return __uint_as_float(u << 16); }
__device__ __forceinline__ float bfhi(unsigned u) { return __uint_as_float(u & 0xffff0000u); }

// ---------------- phase 1 (R19 verbatim): direct binning into 782 half-slabs --
__global__ __launch_bounds__(512) void phase1(
        const float* __restrict__ fvals, const int* __restrict__ frows,
        const int* __restrict__ fcols,
        const float* __restrict__ avals, const int* __restrict__ arows,
        const int* __restrict__ acols,
        int* __restrict__ bcur_x, int* __restrict__ bcur_a,
        float2* __restrict__ gx, float2* __restrict__ ga) {
    const int isA = blockIdx.y;
    const float* vals = isA ? avals : fvals;
    const int* rows   = isA ? arows : frows;
    const int* cols   = isA ? acols : fcols;
    int* bcur         = isA ? bcur_a : bcur_x;
    float2* dst       = isA ? ga : gx;
    const unsigned cap = isA ? CAPAH : CAPXH;
    const unsigned n  = isA ? N_EDGES : NNZ_X;

    unsigned t = threadIdx.x;
    unsigned base = blockIdx.x * CHUNK;
    if (base >= n) return;

    __shared__ int cnt[1024];
    __shared__ int start[1024];
    __shared__ int gofs[NBH];
    __shared__ int wtot[8];
    __shared__ int s_nvalid;
    __shared__ unsigned long long payload[CHUNK];   // 32 KB: (valbits<<32)|(col<<7)|rowlow
    __shared__ unsigned short bkt[CHUNK];           // 8 KB

    int   rcache[KPT];
    float vcache[KPT];
    int   ccache[KPT];

    cnt[t] = 0;
    cnt[t + 512] = 0;
    __syncthreads();
    #pragma unroll
    for (int k = 0; k < KPT; k++) {
        unsigned i = base + k * 512u + t;
        int r = -1;
        if (i < n) {
            int rr = rows[i];
            float v = vals[i];          // coalesced, up-front
            int   c = cols[i];          // coalesced, up-front
            if (isA || keep_42(i)) {
                r = rr;
                vcache[k] = isA ? v : v * (float)(1.0 / 0.9);
                ccache[k] = c;
            }
        }
        rcache[k] = r;
        if (r >= 0) atomicAdd(&cnt[(unsigned)r >> 7], 1);
    }
    __syncthreads();
    // pair-scan over 1024 bins: thread t owns bins 2t, 2t+1; 8-wave shfl scan
    unsigned lane = t & 63u, wid = t >> 6;
    int c0 = cnt[2 * t], c1 = cnt[2 * t + 1];
    int pairsum = c0 + c1;
    int inc = pairsum;
    #pragma unroll
    for (int d = 1; d < 64; d <<= 1) {
        int v = __shfl_up(inc, d, 64);
        if (lane >= (unsigned)d) inc += v;
    }
    if (lane == 63u) wtot[wid] = inc;
    __syncthreads();
    int offw = 0;
    #pragma unroll
    for (int w = 0; w < 8; w++) if ((unsigned)w < wid) offw += wtot[w];
    int excl = offw + inc - pairsum;
    start[2 * t]     = excl;
    start[2 * t + 1] = excl + c0;
    if (t == 511u) s_nvalid = excl + pairsum;
    __syncthreads();
    for (unsigned bb = t; bb < NBH; bb += 512u) {
        int cb = cnt[bb];
        if (cb > 0) {
            int g = atomicAdd(&bcur[bb], cb);
            gofs[bb] = g - start[bb];
        }
    }
    __syncthreads();
    int n_valid = s_nvalid;
    #pragma unroll
    for (int k = 0; k < KPT; k++) {
        int r = rcache[k];
        if (r >= 0) {
            unsigned b = (unsigned)r >> 7;
            int p = atomicAdd(&start[b], 1);
            unsigned packed = ((unsigned)ccache[k] << 7) | ((unsigned)r & 127u);
            payload[p] = ((unsigned long long)__float_as_uint(vcache[k]) << 32) | packed;
            bkt[p] = (unsigned short)b;
        }
    }
    __syncthreads();
    #pragma unroll
    for (int k = 0; k < KPT; k++) {
        int sidx = k * 512 + (int)t;
        if (sidx < n_valid) {
            unsigned b = bkt[sidx];
            unsigned long long m = payload[sidx];
            float2 e;
            e.x = __uint_as_float((unsigned)(m >> 32));
            e.y = __int_as_float((int)(unsigned)m);
            dst[(size_t)b * cap + gofs[b] + sidx] = e;
        }
    }
}

// ---------------- sort_x_spmm1 (R20): writes SLICED xw layout ------------------
// xw = [4][XW_ROWS][16 bf16 dims]; slice p is a contiguous 3.2 MB array so the
// SpMM2 pass-p gather working set fits a 4 MB per-XCD L2.
__global__ __launch_bounds__(512) void sort_x_spmm1(
        const int* __restrict__ bcur_x, const float2* __restrict__ gx,
        const float* __restrict__ W, unsigned short* __restrict__ xw) {
    __shared__ float2 ent[CAPXH];      // 20 KB
    __shared__ int hist[128];
    __shared__ int starts[128];
    __shared__ int cursor[128];
    __shared__ int wtot[2];
    unsigned t = threadIdx.x;
    unsigned wid = t >> 6, lane = t & 63u;
    unsigned b = blockIdx.x;
    int cnt = bcur_x[b];
    const float2* src = gx + (size_t)b * CAPXH;

    if (t < 128) hist[t] = 0;
    __syncthreads();
    float2 ec[5];                       // 5*512 = 2560 = CAPXH
    #pragma unroll
    for (int k = 0; k < 5; k++) {
        int i = k * 512 + (int)t;
        if (i < cnt) {
            float2 e = src[i];
            ec[k] = e;
            atomicAdd(&hist[((unsigned)__float_as_int(e.y)) & 127u], 1);
        }
    }
    __syncthreads();
    int inc = 0, binv = 0;
    if (wid < 2u) {
        unsigned bin = wid * 64u + lane;
        binv = hist[bin];
        inc = binv;
        #pragma unroll
        for (int d = 1; d < 64; d <<= 1) {
            int v = __shfl_up(inc, d, 64);
            if (lane >= (unsigned)d) inc += v;
        }
        if (lane == 63u) wtot[wid] = inc;
    }
    __syncthreads();
    if (wid < 2u) {
        unsigned bin = wid * 64u + lane;
        int excl = inc - binv + (wid == 1u ? wtot[0] : 0);
        starts[bin] = excl;
        cursor[bin] = excl;
    }
    __syncthreads();
    #pragma unroll
    for (int k = 0; k < 5; k++) {
        int i = k * 512 + (int)t;
        if (i < cnt) {
            float2 e = ec[k];
            int pos = atomicAdd(&cursor[((unsigned)__float_as_int(e.y)) & 127u], 1);
            ent[pos] = e;
        }
    }
    __syncthreads();
    // SpMM1: 8 waves x 16 rows; quarter-wave float4 W gathers
    unsigned quarter = lane >> 4, sub = lane & 15u;
    const float4* W4 = (const float4*)W;       // row stride 16 float4
    uint2* xws = (uint2*)xw;                   // sliced: [4][XW_ROWS][4 uint2]
    for (unsigned r = wid; r < 128u; r += 8u) {
        int s0 = starts[r];
        int s1 = (r == 127u) ? cnt : starts[r + 1];
        float4 acc[4];
        #pragma unroll
        for (int j = 0; j < 4; j++) { acc[j].x = acc[j].y = acc[j].z = acc[j].w = 0.0f; }
        int p = s0;
        for (; p + 16 <= s1; p += 16) {
            float2 e[4];
            #pragma unroll
            for (int j = 0; j < 4; j++) e[j] = ent[p + 4 * quarter + j];
            float4 w[4];
            #pragma unroll
            for (int j = 0; j < 4; j++)
                w[j] = W4[(((unsigned)__float_as_int(e[j].y)) >> 7) * 16u + sub];
            #pragma unroll
            for (int j = 0; j < 4; j++) {
                acc[j].x = fmaf(e[j].x, w[j].x, acc[j].x);
                acc[j].y = fmaf(e[j].x, w[j].y, acc[j].y);
                acc[j].z = fmaf(e[j].x, w[j].z, acc[j].z);
                acc[j].w = fmaf(e[j].x, w[j].w, acc[j].w);
            }
        }
        for (int q = p + (int)quarter; q < s1; q += 4) {
            float2 e = ent[q];
            float4 w = W4[(((unsigned)__float_as_int(e.y)) >> 7) * 16u + sub];
            acc[0].x = fmaf(e.x, w.x, acc[0].x);
            acc[0].y = fmaf(e.x, w.y, acc[0].y);
            acc[0].z = fmaf(e.x, w.z, acc[0].z);
            acc[0].w = fmaf(e.x, w.w, acc[0].w);
        }
        float ax = (acc[0].x + acc[1].x) + (acc[2].x + acc[3].x);
        float ay = (acc[0].y + acc[1].y) + (acc[2].y + acc[3].y);
        float az = (acc[0].z + acc[1].z) + (acc[2].z + acc[3].z);
        float aw = (acc[0].w + acc[1].w) + (acc[2].w + acc[3].w);
        ax += __shfl(ax, (int)(lane ^ 16u), 64);
        ay += __shfl(ay, (int)(lane ^ 16u), 64);
        az += __shfl(az, (int)(lane ^ 16u), 64);
        aw += __shfl(aw, (int)(lane ^ 16u), 64);
        ax += __shfl(ax, (int)(lane ^ 32u), 64);
        ay += __shfl(ay, (int)(lane ^ 32u), 64);
        az += __shfl(az, (int)(lane ^ 32u), 64);
        aw += __shfl(aw, (int)(lane ^ 32u), 64);
        unsigned grow = (b << 7) + r;
        if (quarter == 0 && grow < N_NODES) {
            // lane sub holds dims [4sub, 4sub+4) -> slice p = sub>>2,
            // uint2 index within slice row = sub&3
            unsigned sl = sub >> 2;
            uint2 q2;
            q2.x = (unsigned)f32_bf16(ax) | ((unsigned)f32_bf16(ay) << 16);
            q2.y = (unsigned)f32_bf16(az) | ((unsigned)f32_bf16(aw) << 16);
            xws[(size_t)sl * (XW_ROWS * 4u) + grow * 4u + (sub & 3u)] = q2;
        }
    }
}

// ---------------- sort_a_spmm2 (R20): 4-pass dimension-sliced gather ----------
// Sort part unchanged. SpMM2 runs 4 passes; pass p gathers only slice p
// (3.2 MB contiguous, L2-resident) — one dword per lane per edge.
__global__ __launch_bounds__(512) void sort_a_spmm2(
        const int* __restrict__ bcur_a, const float2* __restrict__ ga,
        const unsigned short* __restrict__ xw, float* __restrict__ out) {
    __shared__ float2 ent[CAPAH];      // 24.6 KB
    __shared__ int hist[128];
    __shared__ int starts[128];
    __shared__ int cursor[128];
    __shared__ int wtot[2];
    unsigned t = threadIdx.x;
    unsigned wid = t >> 6, lane = t & 63u;
    unsigned b = blockIdx.x;
    int cnt = bcur_a[b];
    const float2* src = ga + (size_t)b * CAPAH;

    if (t < 128) hist[t] = 0;
    __syncthreads();
    float2 ec[6];                       // 6*512 = 3072 = CAPAH
    #pragma unroll
    for (int k = 0; k < 6; k++) {
        int i = k * 512 + (int)t;
        if (i < cnt) {
            float2 e = src[i];
            ec[k] = e;
            atomicAdd(&hist[((unsigned)__float_as_int(e.y)) & 127u], 1);
        }
    }
    __syncthreads();
    int inc = 0, binv = 0;
    if (wid < 2u) {
        unsigned bin = wid * 64u + lane;
        binv = hist[bin];
        inc = binv;
        #pragma unroll
        for (int d = 1; d < 64; d <<= 1) {
            int v = __shfl_up(inc, d, 64);
            if (lane >= (unsigned)d) inc += v;
        }
        if (lane == 63u) wtot[wid] = inc;
    }
    __syncthreads();
    if (wid < 2u) {
        unsigned bin = wid * 64u + lane;
        int excl = inc - binv + (wid == 1u ? wtot[0] : 0);
        starts[bin] = excl;
        cursor[bin] = excl;
    }
    __syncthreads();
    #pragma unroll
    for (int k = 0; k < 6; k++) {
        int i = k * 512 + (int)t;
        if (i < cnt) {
            float2 e = ec[k];
            int pos = atomicAdd(&cursor[((unsigned)__float_as_int(e.y)) & 127u], 1);
            ent[pos] = e;
        }
    }
    __syncthreads();
    // SpMM2: 4 passes x (8 waves x 16 rows); oct-scheme, dword gathers
    unsigned oct = lane >> 3, sub = lane & 7u;
    #pragma unroll 1
    for (unsigned sl = 0; sl < 4u; sl++) {
        const unsigned* xwp = (const unsigned*)xw + (size_t)sl * (XW_ROWS * 8u);
        #pragma unroll 1
        for (unsigned r = wid; r < 128u; r += 8u) {
            int s0 = starts[r];
            int s1 = (r == 127u) ? cnt : starts[r + 1];
            float a0 = 0.0f, a1 = 0.0f;
            int p = s0 + (int)oct;
            for (; p + 8 < s1; p += 16) {
                float2 e0 = ent[p];
                float2 e1 = ent[p + 8];
                unsigned u0 = xwp[(((unsigned)__float_as_int(e0.y)) >> 7) * 8u + sub];
                unsigned u1 = xwp[(((unsigned)__float_as_int(e1.y)) >> 7) * 8u + sub];
                a0 = fmaf(e0.x, bflo(u0), a0);
                a1 = fmaf(e0.x, bfhi(u0), a1);
                a0 = fmaf(e1.x, bflo(u1), a0);
                a1 = fmaf(e1.x, bfhi(u1), a1);
            }
            if (p < s1) {
                float2 e = ent[p];
                unsigned u = xwp[(((unsigned)__float_as_int(e.y)) >> 7) * 8u + sub];
                a0 = fmaf(e.x, bflo(u), a0);
                a1 = fmaf(e.x, bfhi(u), a1);
            }
            a0 += __shfl_xor(a0, 8, 64);
            a1 += __shfl_xor(a1, 8, 64);
            a0 += __shfl_xor(a0, 16, 64);
            a1 += __shfl_xor(a1, 16, 64);
            a0 += __shfl_xor(a0, 32, 64);
            a1 += __shfl_xor(a1, 32, 64);
            unsigned grow = (b << 7) + r;
            if (oct == 0 && grow < N_NODES) {
                float2 o;
                o.x = fmaxf(a0, 0.0f);
                o.y = fmaxf(a1, 0.0f);
                *(float2*)(out + (size_t)grow * 64u + sl * 16u + sub * 2u) = o;
            }
        }
    }
}

extern "C" void kernel_launch(void* const* d_in, const int* in_sizes, int n_in,
                              void* d_out, int out_size, void* d_ws, size_t ws_size,
                              hipStream_t stream) {
    const float* feat_values = (const float*)d_in[0];
    const float* W           = (const float*)d_in[1];
    const float* adj_values  = (const float*)d_in[2];
    const int*   feat_rows   = (const int*)d_in[3];
    const int*   feat_cols   = (const int*)d_in[4];
    const int*   adj_rows    = (const int*)d_in[5];
    const int*   adj_cols    = (const int*)d_in[6];
    float* out = (float*)d_out;

    // ---- workspace layout (bytes) ----
    char* ws = (char*)d_ws;
    int* bcur_x = (int*)(ws + 0);          // 782 ints
    int* bcur_a = (int*)(ws + 4096);       // 782 ints
    float2* gx  = (float2*)(ws + 16384);                  // 782*2560*8 = 16,015,360
    float2* ga  = (float2*)(ws + 16384 + 16015360);       // 782*3072*8 = 19,218,432
    unsigned short* xw = (unsigned short*)(ws + 35250176); // 4*100096*32 B = 12,812,288

    hipMemsetAsync(ws, 0, 8192, stream);    // bucket cursors

    dim3 gp1((N_EDGES + CHUNK - 1) / CHUNK, 2);
    phase1<<<gp1, 512, 0, stream>>>(feat_values, feat_rows, feat_cols,
                                    adj_values, adj_rows, adj_cols,
                                    bcur_x, bcur_a, gx, ga);
    sort_x_spmm1<<<NBH, 512, 0, stream>>>(bcur_x, gx, W, xw);
    sort_a_spmm2<<<NBH, 512, 0, stream>>>(bcur_a, ga, xw, out);
}

// Round 9
// 178.600 us; speedup vs baseline: 1.1509x; 1.1509x over previous
//
#include <hip/hip_runtime.h>

#define N_NODES 100000
#define N_FEATS 256
#define OUT_DIM 64
#define NNZ_X   1280000
#define N_EDGES 1600000
#define NBH     782     // ceil(N_NODES/128); bucket = row >> 7 (half-buckets)
#define CHUNK   4096    // entries per phase-1 block (512 thr, 8/thread)
#define KPT     8
#define CAPXH   2560    // X half-slab capacity (kept-mean 1473, sigma ~38: +28 sigma)
#define CAPAH   3072    // A half-slab capacity (mean 2046, sigma ~45: +22 sigma)

// ---------------- JAX threefry2x32 (partitionable mode, verified R2) ----------------
__device__ __forceinline__ unsigned rotl32(unsigned x, unsigned d) {
    return (x << d) | (x >> (32u - d));
}

__device__ __forceinline__ float jax_uniform_42(unsigned e) {
    unsigned x0 = 0u, x1 = e;
    const unsigned ks0 = 0u, ks1 = 42u, ks2 = 0u ^ 42u ^ 0x1BD11BDAu;
    x0 += ks0; x1 += ks1;
#define TF_R(r) { x0 += x1; x1 = rotl32(x1, r); x1 ^= x0; }
    TF_R(13) TF_R(15) TF_R(26) TF_R(6)
    x0 += ks1; x1 += ks2 + 1u;
    TF_R(17) TF_R(29) TF_R(16) TF_R(24)
    x0 += ks2; x1 += ks0 + 2u;
    TF_R(13) TF_R(15) TF_R(26) TF_R(6)
    x0 += ks0; x1 += ks1 + 3u;
    TF_R(17) TF_R(29) TF_R(16) TF_R(24)
    x0 += ks1; x1 += ks2 + 4u;
    TF_R(13) TF_R(15) TF_R(26) TF_R(6)
    x0 += ks2; x1 += ks0 + 5u;
#undef TF_R
    unsigned bits = x0 ^ x1;
    return __uint_as_float((bits >> 9) | 0x3f800000u) - 1.0f;
}

__device__ __forceinline__ bool keep_42(unsigned e) {
    float u = jax_uniform_42(e);
    return floorf(0.9f + u) != 0.0f;
}

// f32 -> bf16 round-to-nearest-even
__device__ __forceinline__ unsigned short f32_bf16(float f) {
    unsigned bits = __float_as_uint(f);
    return (unsigned short)((bits + 0x7fffu + ((bits >> 16) & 1u)) >> 16);
}

__device__ __forceinline__ float bflo(unsigned u) { return __uint_as_float(u << 16); }
__device__ __forceinline__ float bfhi(unsigned u) { return __uint_as_float(u & 0xffff0000u); }

// ---------------- phase 1 (R19 verbatim): direct binning into 782 half-slabs --
__global__ __launch_bounds__(512) void phase1(
        const float* __restrict__ fvals, const int* __restrict__ frows,
        const int* __restrict__ fcols,
        const float* __restrict__ avals, const int* __restrict__ arows,
        const int* __restrict__ acols,
        int* __restrict__ bcur_x, int* __restrict__ bcur_a,
        float2* __restrict__ gx, float2* __restrict__ ga) {
    const int isA = blockIdx.y;
    const float* vals = isA ? avals : fvals;
    const int* rows   = isA ? arows : frows;
    const int* cols   = isA ? acols : fcols;
    int* bcur         = isA ? bcur_a : bcur_x;
    float2* dst       = isA ? ga : gx;
    const unsigned cap = isA ? CAPAH : CAPXH;
    const unsigned n  = isA ? N_EDGES : NNZ_X;

    unsigned t = threadIdx.x;
    unsigned base = blockIdx.x * CHUNK;
    if (base >= n) return;

    __shared__ int cnt[1024];
    __shared__ int start[1024];
    __shared__ int gofs[NBH];
    __shared__ int wtot[8];
    __shared__ int s_nvalid;
    __shared__ unsigned long long payload[CHUNK];   // 32 KB: (valbits<<32)|(col<<7)|rowlow
    __shared__ unsigned short bkt[CHUNK];           // 8 KB

    int   rcache[KPT];
    float vcache[KPT];
    int   ccache[KPT];

    cnt[t] = 0;
    cnt[t + 512] = 0;
    __syncthreads();
    #pragma unroll
    for (int k = 0; k < KPT; k++) {
        unsigned i = base + k * 512u + t;
        int r = -1;
        if (i < n) {
            int rr = rows[i];
            float v = vals[i];          // coalesced, up-front
            int   c = cols[i];          // coalesced, up-front
            if (isA || keep_42(i)) {
                r = rr;
                vcache[k] = isA ? v : v * (float)(1.0 / 0.9);
                ccache[k] = c;
            }
        }
        rcache[k] = r;
        if (r >= 0) atomicAdd(&cnt[(unsigned)r >> 7], 1);
    }
    __syncthreads();
    // pair-scan over 1024 bins: thread t owns bins 2t, 2t+1; 8-wave shfl scan
    unsigned lane = t & 63u, wid = t >> 6;
    int c0 = cnt[2 * t], c1 = cnt[2 * t + 1];
    int pairsum = c0 + c1;
    int inc = pairsum;
    #pragma unroll
    for (int d = 1; d < 64; d <<= 1) {
        int v = __shfl_up(inc, d, 64);
        if (lane >= (unsigned)d) inc += v;
    }
    if (lane == 63u) wtot[wid] = inc;
    __syncthreads();
    int offw = 0;
    #pragma unroll
    for (int w = 0; w < 8; w++) if ((unsigned)w < wid) offw += wtot[w];
    int excl = offw + inc - pairsum;
    start[2 * t]     = excl;
    start[2 * t + 1] = excl + c0;
    if (t == 511u) s_nvalid = excl + pairsum;
    __syncthreads();
    for (unsigned bb = t; bb < NBH; bb += 512u) {
        int cb = cnt[bb];
        if (cb > 0) {
            int g = atomicAdd(&bcur[bb], cb);
            gofs[bb] = g - start[bb];
        }
    }
    __syncthreads();
    int n_valid = s_nvalid;
    #pragma unroll
    for (int k = 0; k < KPT; k++) {
        int r = rcache[k];
        if (r >= 0) {
            unsigned b = (unsigned)r >> 7;
            int p = atomicAdd(&start[b], 1);
            unsigned packed = ((unsigned)ccache[k] << 7) | ((unsigned)r & 127u);
            payload[p] = ((unsigned long long)__float_as_uint(vcache[k]) << 32) | packed;
            bkt[p] = (unsigned short)b;
        }
    }
    __syncthreads();
    #pragma unroll
    for (int k = 0; k < KPT; k++) {
        int sidx = k * 512 + (int)t;
        if (sidx < n_valid) {
            unsigned b = bkt[sidx];
            unsigned long long m = payload[sidx];
            float2 e;
            e.x = __uint_as_float((unsigned)(m >> 32));
            e.y = __int_as_float((int)(unsigned)m);
            dst[(size_t)b * cap + gofs[b] + sidx] = e;
        }
    }
}

// ---------------- sort_x_spmm1 (R22): 8-entry batch, 2-deep W gathers ---------
// X rows average 11.5 entries; the old 16-entry main batch almost never ran and
// rows fell into a serial 1-load-in-flight tail. New inner loop: quarter-slot q
// processes entries {q, q+4} per iteration (2 gathers in flight), 1-entry tail.
__global__ __launch_bounds__(512) void sort_x_spmm1(
        const int* __restrict__ bcur_x, const float2* __restrict__ gx,
        const float* __restrict__ W, unsigned short* __restrict__ xw) {
    __shared__ float2 ent[CAPXH];      // 20 KB
    __shared__ int hist[128];
    __shared__ int starts[128];
    __shared__ int cursor[128];
    __shared__ int wtot[2];
    unsigned t = threadIdx.x;
    unsigned wid = t >> 6, lane = t & 63u;
    unsigned b = blockIdx.x;
    int cnt = bcur_x[b];
    const float2* src = gx + (size_t)b * CAPXH;

    if (t < 128) hist[t] = 0;
    __syncthreads();
    float2 ec[5];                       // 5*512 = 2560 = CAPXH
    #pragma unroll
    for (int k = 0; k < 5; k++) {
        int i = k * 512 + (int)t;
        if (i < cnt) {
            float2 e = src[i];
            ec[k] = e;
            atomicAdd(&hist[((unsigned)__float_as_int(e.y)) & 127u], 1);
        }
    }
    __syncthreads();
    int inc = 0, binv = 0;
    if (wid < 2u) {
        unsigned bin = wid * 64u + lane;
        binv = hist[bin];
        inc = binv;
        #pragma unroll
        for (int d = 1; d < 64; d <<= 1) {
            int v = __shfl_up(inc, d, 64);
            if (lane >= (unsigned)d) inc += v;
        }
        if (lane == 63u) wtot[wid] = inc;
    }
    __syncthreads();
    if (wid < 2u) {
        unsigned bin = wid * 64u + lane;
        int excl = inc - binv + (wid == 1u ? wtot[0] : 0);
        starts[bin] = excl;
        cursor[bin] = excl;
    }
    __syncthreads();
    #pragma unroll
    for (int k = 0; k < 5; k++) {
        int i = k * 512 + (int)t;
        if (i < cnt) {
            float2 e = ec[k];
            int pos = atomicAdd(&cursor[((unsigned)__float_as_int(e.y)) & 127u], 1);
            ent[pos] = e;
        }
    }
    __syncthreads();
    // SpMM1: 8 waves x 16 rows; quarter-slot 8-entry batches, 2-deep
    unsigned quarter = lane >> 4, sub = lane & 15u;
    const float4* W4 = (const float4*)W;       // row stride 16 float4
    ushort4* xw4 = (ushort4*)xw;               // row stride 16 ushort4
    for (unsigned r = wid; r < 128u; r += 8u) {
        int s0 = starts[r];
        int s1 = (r == 127u) ? cnt : starts[r + 1];
        float4 acc0, acc1;
        acc0.x = acc0.y = acc0.z = acc0.w = 0.0f;
        acc1.x = acc1.y = acc1.z = acc1.w = 0.0f;
        int p = s0 + (int)quarter;
        for (; p + 4 < s1; p += 8) {
            float2 e0 = ent[p];
            float2 e1 = ent[p + 4];
            float4 w0 = W4[(((unsigned)__float_as_int(e0.y)) >> 7) * 16u + sub];
            float4 w1 = W4[(((unsigned)__float_as_int(e1.y)) >> 7) * 16u + sub];
            acc0.x = fmaf(e0.x, w0.x, acc0.x);
            acc0.y = fmaf(e0.x, w0.y, acc0.y);
            acc0.z = fmaf(e0.x, w0.z, acc0.z);
            acc0.w = fmaf(e0.x, w0.w, acc0.w);
            acc1.x = fmaf(e1.x, w1.x, acc1.x);
            acc1.y = fmaf(e1.x, w1.y, acc1.y);
            acc1.z = fmaf(e1.x, w1.z, acc1.z);
            acc1.w = fmaf(e1.x, w1.w, acc1.w);
        }
        if (p < s1) {
            float2 e = ent[p];
            float4 w = W4[(((unsigned)__float_as_int(e.y)) >> 7) * 16u + sub];
            acc0.x = fmaf(e.x, w.x, acc0.x);
            acc0.y = fmaf(e.x, w.y, acc0.y);
            acc0.z = fmaf(e.x, w.z, acc0.z);
            acc0.w = fmaf(e.x, w.w, acc0.w);
        }
        float ax = acc0.x + acc1.x;
        float ay = acc0.y + acc1.y;
        float az = acc0.z + acc1.z;
        float aw = acc0.w + acc1.w;
        ax += __shfl(ax, (int)(lane ^ 16u), 64);
        ay += __shfl(ay, (int)(lane ^ 16u), 64);
        az += __shfl(az, (int)(lane ^ 16u), 64);
        aw += __shfl(aw, (int)(lane ^ 16u), 64);
        ax += __shfl(ax, (int)(lane ^ 32u), 64);
        ay += __shfl(ay, (int)(lane ^ 32u), 64);
        az += __shfl(az, (int)(lane ^ 32u), 64);
        aw += __shfl(aw, (int)(lane ^ 32u), 64);
        unsigned grow = (b << 7) + r;
        if (quarter == 0 && grow < N_NODES) {
            ushort4 o;
            o.x = f32_bf16(ax); o.y = f32_bf16(ay);
            o.z = f32_bf16(az); o.w = f32_bf16(aw);
            xw4[(size_t)grow * 16u + sub] = o;
        }
    }
}

// ---------------- sort_a_spmm2 (R19 verbatim): half-slab sort + SpMM2 + ReLU --
__global__ __launch_bounds__(512) void sort_a_spmm2(
        const int* __restrict__ bcur_a, const float2* __restrict__ ga,
        const unsigned short* __restrict__ xw, float* __restrict__ out) {
    __shared__ float2 ent[CAPAH];      // 24.6 KB
    __shared__ int hist[128];
    __shared__ int starts[128];
    __shared__ int cursor[128];
    __shared__ int wtot[2];
    unsigned t = threadIdx.x;
    unsigned wid = t >> 6, lane = t & 63u;
    unsigned b = blockIdx.x;
    int cnt = bcur_a[b];
    const float2* src = ga + (size_t)b * CAPAH;

    if (t < 128) hist[t] = 0;
    __syncthreads();
    float2 ec[6];                       // 6*512 = 3072 = CAPAH
    #pragma unroll
    for (int k = 0; k < 6; k++) {
        int i = k * 512 + (int)t;
        if (i < cnt) {
            float2 e = src[i];
            ec[k] = e;
            atomicAdd(&hist[((unsigned)__float_as_int(e.y)) & 127u], 1);
        }
    }
    __syncthreads();
    int inc = 0, binv = 0;
    if (wid < 2u) {
        unsigned bin = wid * 64u + lane;
        binv = hist[bin];
        inc = binv;
        #pragma unroll
        for (int d = 1; d < 64; d <<= 1) {
            int v = __shfl_up(inc, d, 64);
            if (lane >= (unsigned)d) inc += v;
        }
        if (lane == 63u) wtot[wid] = inc;
    }
    __syncthreads();
    if (wid < 2u) {
        unsigned bin = wid * 64u + lane;
        int excl = inc - binv + (wid == 1u ? wtot[0] : 0);
        starts[bin] = excl;
        cursor[bin] = excl;
    }
    __syncthreads();
    #pragma unroll
    for (int k = 0; k < 6; k++) {
        int i = k * 512 + (int)t;
        if (i < cnt) {
            float2 e = ec[k];
            int pos = atomicAdd(&cursor[((unsigned)__float_as_int(e.y)) & 127u], 1);
            ent[pos] = e;
        }
    }
    __syncthreads();
    // SpMM2: 8 waves x 16 rows; oct-scheme (8 edge slots x 8 dim-octets), R4 form
    unsigned oct = lane >> 3, sub = lane & 7u;
    const uint4* xw8 = (const uint4*)xw;   // row stride = 8 uint4 (128B)
    for (unsigned r = wid; r < 128u; r += 8u) {
        int s0 = starts[r];
        int s1 = (r == 127u) ? cnt : starts[r + 1];
        float acc[8];
        #pragma unroll
        for (int j = 0; j < 8; j++) acc[j] = 0.0f;
        int p = s0 + (int)oct;
        for (; p + 8 < s1; p += 16) {
            float2 e0 = ent[p];
            float2 e1 = ent[p + 8];
            uint4 u0 = xw8[(((unsigned)__float_as_int(e0.y)) >> 7) * 8u + sub];
            uint4 u1 = xw8[(((unsigned)__float_as_int(e1.y)) >> 7) * 8u + sub];
            float v0 = e0.x, v1 = e1.x;
            acc[0] = fmaf(v0, bflo(u0.x), acc[0]);
            acc[1] = fmaf(v0, bfhi(u0.x), acc[1]);
            acc[2] = fmaf(v0, bflo(u0.y), acc[2]);
            acc[3] = fmaf(v0, bfhi(u0.y), acc[3]);
            acc[4] = fmaf(v0, bflo(u0.z), acc[4]);
            acc[5] = fmaf(v0, bfhi(u0.z), acc[5]);
            acc[6] = fmaf(v0, bflo(u0.w), acc[6]);
            acc[7] = fmaf(v0, bfhi(u0.w), acc[7]);
            acc[0] = fmaf(v1, bflo(u1.x), acc[0]);
            acc[1] = fmaf(v1, bfhi(u1.x), acc[1]);
            acc[2] = fmaf(v1, bflo(u1.y), acc[2]);
            acc[3] = fmaf(v1, bfhi(u1.y), acc[3]);
            acc[4] = fmaf(v1, bflo(u1.z), acc[4]);
            acc[5] = fmaf(v1, bfhi(u1.z), acc[5]);
            acc[6] = fmaf(v1, bflo(u1.w), acc[6]);
            acc[7] = fmaf(v1, bfhi(u1.w), acc[7]);
        }
        if (p < s1) {
            float2 e = ent[p];
            uint4 u = xw8[(((unsigned)__float_as_int(e.y)) >> 7) * 8u + sub];
            float v = e.x;
            acc[0] = fmaf(v, bflo(u.x), acc[0]);
            acc[1] = fmaf(v, bfhi(u.x), acc[1]);
            acc[2] = fmaf(v, bflo(u.y), acc[2]);
            acc[3] = fmaf(v, bfhi(u.y), acc[3]);
            acc[4] = fmaf(v, bflo(u.z), acc[4]);
            acc[5] = fmaf(v, bfhi(u.z), acc[5]);
            acc[6] = fmaf(v, bflo(u.w), acc[6]);
            acc[7] = fmaf(v, bfhi(u.w), acc[7]);
        }
        #pragma unroll
        for (int j = 0; j < 8; j++) {
            acc[j] += __shfl_xor(acc[j], 8, 64);
            acc[j] += __shfl_xor(acc[j], 16, 64);
            acc[j] += __shfl_xor(acc[j], 32, 64);
        }
        unsigned grow = (b << 7) + r;
        if (oct == 0 && grow < N_NODES) {
            float4 o0, o1;
            o0.x = fmaxf(acc[0], 0.0f);
            o0.y = fmaxf(acc[1], 0.0f);
            o0.z = fmaxf(acc[2], 0.0f);
            o0.w = fmaxf(acc[3], 0.0f);
            o1.x = fmaxf(acc[4], 0.0f);
            o1.y = fmaxf(acc[5], 0.0f);
            o1.z = fmaxf(acc[6], 0.0f);
            o1.w = fmaxf(acc[7], 0.0f);
            float4* op = (float4*)(out + (size_t)grow * 64u + sub * 8u);
            op[0] = o0;
            op[1] = o1;
        }
    }
}

extern "C" void kernel_launch(void* const* d_in, const int* in_sizes, int n_in,
                              void* d_out, int out_size, void* d_ws, size_t ws_size,
                              hipStream_t stream) {
    const float* feat_values = (const float*)d_in[0];
    const float* W           = (const float*)d_in[1];
    const float* adj_values  = (const float*)d_in[2];
    const int*   feat_rows   = (const int*)d_in[3];
    const int*   feat_cols   = (const int*)d_in[4];
    const int*   adj_rows    = (const int*)d_in[5];
    const int*   adj_cols    = (const int*)d_in[6];
    float* out = (float*)d_out;

    // ---- workspace layout (bytes) ----
    char* ws = (char*)d_ws;
    int* bcur_x = (int*)(ws + 0);          // 782 ints
    int* bcur_a = (int*)(ws + 4096);       // 782 ints
    float2* gx  = (float2*)(ws + 16384);                  // 782*2560*8 = 16,015,360
    float2* ga  = (float2*)(ws + 16384 + 16015360);       // 782*3072*8 = 19,218,432
    unsigned short* xw = (unsigned short*)(ws + 35250176); // 100096*128 B

    hipMemsetAsync(ws, 0, 8192, stream);    // bucket cursors

    dim3 gp1((N_EDGES + CHUNK - 1) / CHUNK, 2);
    phase1<<<gp1, 512, 0, stream>>>(feat_values, feat_rows, feat_cols,
                                    adj_values, adj_rows, adj_cols,
                                    bcur_x, bcur_a, gx, ga);
    sort_x_spmm1<<<NBH, 512, 0, stream>>>(bcur_x, gx, W, xw);
    sort_a_spmm2<<<NBH, 512, 0, stream>>>(bcur_a, ga, xw, out);
}